// Round 18
// baseline (81.279 us; speedup 1.0000x reference)
//
#include <hip/hip_runtime.h>
#include <hip/hip_bf16.h>

typedef __bf16 bf16x8 __attribute__((ext_vector_type(8)));
typedef float f32x4 __attribute__((ext_vector_type(4)));
typedef float f32x16 __attribute__((ext_vector_type(16)));

__device__ inline unsigned short f2bf(float f) {
    __hip_bfloat16 h = __float2bfloat16(f);
    return __builtin_bit_cast(unsigned short, h);
}
__device__ inline unsigned pk2bf(float a, float b) {
    return (unsigned)f2bf(a) | ((unsigned)f2bf(b) << 16);
}
__device__ inline float exp2_fast(float x) {
    float r;
    asm("v_exp_f32 %0, %1" : "=v"(r) : "v"(x));
    return r;
}

#define QSCALE 0.1803368801111244f  /* 0.125 * log2(e) */

// ------- fused projection + V-transpose: flat grid 768, XCD m-tile affinity ----------
// decode: xcd=flat&7, i=flat>>3 (0..95), mi=i/12, by=i%12, bm=(xcd*8+mi)*128.
// by 0..3: Q = (x Wq^T)*QSCALE; by 4..7: K = x Wk^T; by 8..11: V transpose slice.
// GEMM K-loop is SOFTWARE-PIPELINED (round-18): register prefetch 1 tile ahead +
// double-buffered LDS -> 1 barrier/tile, global latency hides under MFMA+cvt.
__global__ __launch_bounds__(256) void gemm_qk(const float* __restrict__ x,
                                               const float* __restrict__ Wq,
                                               const float* __restrict__ Wk,
                                               unsigned short* __restrict__ Qb,
                                               unsigned short* __restrict__ Kb,
                                               unsigned short* __restrict__ Vt) {
    __shared__ __align__(16) unsigned short sA0[128 * 40];
    __shared__ __align__(16) unsigned short sB0[128 * 40];
    __shared__ __align__(16) unsigned short sA1[128 * 40];
    __shared__ __align__(16) unsigned short sB1[128 * 40];
    const int tid  = threadIdx.x;
    const int flat = blockIdx.x;
    const int xcd  = flat & 7;
    const int i    = flat >> 3;          // 0..95
    const int mi   = i / 12;             // 0..7
    const int by   = i - mi * 12;        // 0..11
    const int bm   = (xcd * 8 + mi) * 128;

    if (by >= 8) {  // ---- V transpose slice ----
        const int q = by - 8;
        const int nl = tid & 127, hh = tid >> 7;
        const int h = q * 2 + hh;
        const int g = bm + nl;                     // global row 0..8191
        const int b = g >> 11, n = g & 2047;
        const int np = (n & ~15) | (n & 3) | ((n & 4) << 1) | ((n & 8) >> 1);
        const size_t xrow = ((size_t)b * 2048 + n) * 512 + h * 64;
        const size_t vbase = ((size_t)(b * 8 + h) * 64) * 2048 + np;
#pragma unroll
        for (int d0 = 0; d0 < 64; d0 += 4) {
            float4 v = *reinterpret_cast<const float4*>(&x[xrow + d0]);
            Vt[vbase + (size_t)(d0 + 0) * 2048] = f2bf(v.x);
            Vt[vbase + (size_t)(d0 + 1) * 2048] = f2bf(v.y);
            Vt[vbase + (size_t)(d0 + 2) * 2048] = f2bf(v.z);
            Vt[vbase + (size_t)(d0 + 3) * 2048] = f2bf(v.w);
        }
        return;
    }

    const int lane = tid & 63;
    const int wave = tid >> 6;
    const int wr = wave >> 1, wc = wave & 1;
    const float* __restrict__ Bsrc = (by < 4) ? Wq : Wk;
    unsigned short* __restrict__ C = (by < 4) ? Qb : Kb;
    const int bn = (by & 3) * 128;
    const float scale = (by < 4) ? QSCALE : 1.0f;
    const int tr = tid >> 1, th = (tid & 1) * 16;
    const int rl = lane & 15;
    const int kq = (lane >> 4) * 8;

    f32x4 acc[4][4];
#pragma unroll
    for (int m = 0; m < 4; ++m)
#pragma unroll
        for (int n = 0; n < 4; ++n) acc[m][n] = (f32x4){0.f, 0.f, 0.f, 0.f};

    float4 ra0, ra1, ra2, ra3, rb0, rb1, rb2, rb3;
    auto ldt = [&](int k0) {
        const float* ap = &x[(size_t)(bm + tr) * 512 + k0 + th];
        const float* bp = &Bsrc[(size_t)(bn + tr) * 512 + k0 + th];
        ra0 = *reinterpret_cast<const float4*>(ap);
        ra1 = *reinterpret_cast<const float4*>(ap + 4);
        ra2 = *reinterpret_cast<const float4*>(ap + 8);
        ra3 = *reinterpret_cast<const float4*>(ap + 12);
        rb0 = *reinterpret_cast<const float4*>(bp);
        rb1 = *reinterpret_cast<const float4*>(bp + 4);
        rb2 = *reinterpret_cast<const float4*>(bp + 8);
        rb3 = *reinterpret_cast<const float4*>(bp + 12);
    };
    auto wrt = [&](unsigned short* SA, unsigned short* SB) {
        uint4 pa0 = {pk2bf(ra0.x, ra0.y), pk2bf(ra0.z, ra0.w), pk2bf(ra1.x, ra1.y), pk2bf(ra1.z, ra1.w)};
        uint4 pa1 = {pk2bf(ra2.x, ra2.y), pk2bf(ra2.z, ra2.w), pk2bf(ra3.x, ra3.y), pk2bf(ra3.z, ra3.w)};
        uint4 pb0 = {pk2bf(rb0.x, rb0.y), pk2bf(rb0.z, rb0.w), pk2bf(rb1.x, rb1.y), pk2bf(rb1.z, rb1.w)};
        uint4 pb1 = {pk2bf(rb2.x, rb2.y), pk2bf(rb2.z, rb2.w), pk2bf(rb3.x, rb3.y), pk2bf(rb3.z, rb3.w)};
        *reinterpret_cast<uint4*>(&SA[tr * 40 + th])     = pa0;
        *reinterpret_cast<uint4*>(&SA[tr * 40 + th + 8]) = pa1;
        *reinterpret_cast<uint4*>(&SB[tr * 40 + th])     = pb0;
        *reinterpret_cast<uint4*>(&SB[tr * 40 + th + 8]) = pb1;
    };
    auto cmp = [&](const unsigned short* SA, const unsigned short* SB) {
        bf16x8 af[4], bfv[4];
#pragma unroll
        for (int m = 0; m < 4; ++m)
            af[m] = __builtin_bit_cast(bf16x8,
                *reinterpret_cast<const uint4*>(&SA[(wr * 64 + m * 16 + rl) * 40 + kq]));
#pragma unroll
        for (int n = 0; n < 4; ++n)
            bfv[n] = __builtin_bit_cast(bf16x8,
                *reinterpret_cast<const uint4*>(&SB[(wc * 64 + n * 16 + rl) * 40 + kq]));
#pragma unroll
        for (int m = 0; m < 4; ++m)
#pragma unroll
            for (int n = 0; n < 4; ++n)
                acc[m][n] = __builtin_amdgcn_mfma_f32_16x16x32_bf16(af[m], bfv[n], acc[m][n], 0, 0, 0);
    };

    // pipelined loop: tile t in LDS buf, t+1 in regs, t+2 loading
    ldt(0);
    wrt(sA0, sB0);
    ldt(32);
    __syncthreads();
    for (int k = 0; k < 512; k += 64) {
        wrt(sA1, sB1);                    // tile k+32 regs -> buf1
        if (k + 64 < 512) ldt(k + 64);    // issue tile k+64 loads
        cmp(sA0, sB0);                    // compute tile k
        __syncthreads();
        if (k + 64 < 512) {
            wrt(sA0, sB0);                // tile k+64 regs -> buf0
            if (k + 96 < 512) ldt(k + 96);
        }
        cmp(sA1, sB1);                    // compute tile k+32
        __syncthreads();
    }

    const int rq = (lane >> 4) * 4;
#pragma unroll
    for (int m = 0; m < 4; ++m) {
        int r = bm + wr * 64 + m * 16 + rq;
#pragma unroll
        for (int n = 0; n < 4; ++n) {
            int c = bn + wc * 64 + n * 16 + rl;
#pragma unroll
            for (int reg = 0; reg < 4; ++reg)
                C[(size_t)(r + reg) * 512 + c] = f2bf(acc[m][n][reg] * scale);
        }
    }
}

// ---------------- fused flash attention: 8 waves (4qh x 2jp), dbuf, 1 barrier/tile ---
// grid: 512 flat blocks, XCD bh-affinity (xcd=flat&7 owns bh {4xcd..4xcd+3}) -> per-XCD
// K/V working set 2MB, L2-resident. block: 512 = 8 waves; wave: qh=w&3, jp=w>>2.
// Fixed-reference softmax in log2 domain (log2e folded into Q-scale and slope).
// One-time sPos table (slopeL*pos, 8KB LDS) removes pos staging from the loop.
// S^T: mfma(K,Q) -> D[row=j][col=q]: lane q=l31, j=(r&3)+8*(r>>2)+4*hi.
// PV: P-frag lane-local, j-map = 16ks + 4hi + (e&3) + 8*(e>>2); V pre-permuted so this
// fragment is one contiguous b128 read. LDS rows XOR-swizzled (byte ^= (row&7)<<4).
__global__ __launch_bounds__(512, 4) void attn_fwd(const unsigned short* __restrict__ Q,
                                                   const unsigned short* __restrict__ Kb,
                                                   const unsigned short* __restrict__ Vt,
                                                   const float* __restrict__ pos,
                                                   float* __restrict__ Out) {
    __shared__ __align__(16) unsigned char smem[42240];
    char* k0b = (char*)smem;                 // 8 KiB
    char* v0b = (char*)smem + 8192;          // 8 KiB
    char* k1b = (char*)smem + 16384;         // 8 KiB
    char* v1b = (char*)smem + 24576;         // 8 KiB
    float* sPosT = (float*)(smem + 32768);   // 2048 f32 slopeL*pos (8 KiB)
    float* sMl   = (float*)(smem + 40960);   // 256 f32 (epilogue l merge)

    const int tid  = threadIdx.x;
    const int lane = tid & 63;
    const int w    = tid >> 6;
    const int l31  = lane & 31;
    const int hi   = lane >> 5;
    const int qh   = w & 3;
    const int jp   = w >> 2;
    // XCD-affine decode (512 blocks, bijective: 512 % 8 == 0)
    const int flat = blockIdx.x;
    const int xcd  = flat & 7;
    const int idx  = flat >> 3;              // 0..63
    const int bh   = xcd * 4 + (idx >> 4);
    const int qt   = idx & 15;
    const int b = bh >> 3, h = bh & 7;
    const int q0 = qt * 128 + qh * 32;
    const size_t rowbase = (size_t)b * 2048;
    const int hc = h * 64;
    const float slopeL = ldexpf(1.4426950408889634f, -(h + 1));  // slope * log2(e)

    // Q B-fragments: lane supplies Q[q=l31][c = ks*16 + hi*8 + e] (Q pre-scaled)
    bf16x8 qf0, qf1, qf2, qf3;
    {
        const unsigned short* qp = &Q[(rowbase + q0 + l31) * 512 + hc + hi * 8];
        qf0 = __builtin_bit_cast(bf16x8, *reinterpret_cast<const uint4*>(qp));
        qf1 = __builtin_bit_cast(bf16x8, *reinterpret_cast<const uint4*>(qp + 16));
        qf2 = __builtin_bit_cast(bf16x8, *reinterpret_cast<const uint4*>(qp + 32));
        qf3 = __builtin_bit_cast(bf16x8, *reinterpret_cast<const uint4*>(qp + 48));
    }
    const float ui = slopeL * pos[rowbase + q0 + l31];

    // one-time slopeL*pos table (512 threads x 4 = 2048)
    {
        float4 v = reinterpret_cast<const float4*>(pos + rowbase)[tid];
        reinterpret_cast<f32x4*>(sPosT)[tid] =
            (f32x4){v.x * slopeL, v.y * slopeL, v.z * slopeL, v.w * slopeL};
    }

    float lloc = 0.f;
    f32x16 o0, o1;
#pragma unroll
    for (int r = 0; r < 16; ++r) { o0[r] = 0.f; o1[r] = 0.f; }

    // staging: 8 threads/row x 16 B; write slot XOR-swizzled -> conflict-free
    const int sr  = tid >> 3;                       // row 0..63
    const int sce = (tid & 7) * 8;                  // elem col (8 elems/thread)
    const int wbyte = sr * 128 + (((tid & 7) * 16) ^ ((sr & 7) << 4));
    const int kswz = (l31 & 7) << 4;                // compute-side swizzle key

    uint4 ck, cv;

    auto stage = [&](int j0v) {
        ck = *reinterpret_cast<const uint4*>(&Kb[(rowbase + j0v + sr) * 512 + hc + sce]);
        cv = *reinterpret_cast<const uint4*>(&Vt[((size_t)bh * 64 + sr) * 2048 + j0v + sce]);
    };
    auto writeb = [&](char* KB, char* VB) {
        *reinterpret_cast<uint4*>(KB + wbyte) = ck;
        *reinterpret_cast<uint4*>(VB + wbyte) = cv;
    };
    auto compute = [&](const char* KB, const char* VB, int j0) {
        const char* kr = KB + (32 * jp + l31) * 128;
        // ---- S chunk (32j x 32q) for this wave's (qh, jp) ----
        f32x16 s;
#pragma unroll
        for (int r = 0; r < 16; ++r) s[r] = 0.f;
        __builtin_amdgcn_s_setprio(1);
#pragma unroll
        for (int ks = 0; ks < 4; ++ks) {
            bf16x8 kf = __builtin_bit_cast(bf16x8,
                *reinterpret_cast<const uint4*>(kr + ((ks * 32 + hi * 16) ^ kswz)));
            bf16x8 qq = (ks == 0) ? qf0 : (ks == 1) ? qf1 : (ks == 2) ? qf2 : qf3;
            s = __builtin_amdgcn_mfma_f32_32x32x16_bf16(kf, qq, s, 0, 0, 0);
        }
        __builtin_amdgcn_s_setprio(0);

        // ---- bias + exp2 (fixed reference, log2 domain) ----
        float ls = 0.f;
#pragma unroll
        for (int t = 0; t < 4; ++t) {
            f32x4 u = *reinterpret_cast<const f32x4*>(&sPosT[j0 + 32 * jp + 8 * t + 4 * hi]);
#pragma unroll
            for (int r = 0; r < 4; ++r) {
                float p = exp2_fast(s[4 * t + r] - fabsf(u[r] - ui));
                s[4 * t + r] = p;
                ls += p;
            }
        }
        lloc += ls;

        // ---- lane-local P fragments (j = 16ks + 4hi + (e&3) + 8*(e>>2)) ----
        bf16x8 pf0 = __builtin_bit_cast(bf16x8, (uint4){
            pk2bf(s[0], s[1]),  pk2bf(s[2], s[3]),   pk2bf(s[4], s[5]),   pk2bf(s[6], s[7])});
        bf16x8 pf1 = __builtin_bit_cast(bf16x8, (uint4){
            pk2bf(s[8], s[9]),  pk2bf(s[10], s[11]), pk2bf(s[12], s[13]), pk2bf(s[14], s[15])});

        // ---- PV: O^T[d][q] += V-frag x P-frag; V pre-permuted -> single b128/frag ----
        const char* vr0 = VB + l31 * 128;
        const char* vr1 = VB + (32 + l31) * 128;
        __builtin_amdgcn_s_setprio(1);
#pragma unroll
        for (int ks = 0; ks < 2; ++ks) {
            const int cb = (64 * jp + ks * 32 + hi * 16) ^ kswz;  // permuted-stored
            bf16x8 v0 = __builtin_bit_cast(bf16x8, *reinterpret_cast<const uint4*>(vr0 + cb));
            bf16x8 v1 = __builtin_bit_cast(bf16x8, *reinterpret_cast<const uint4*>(vr1 + cb));
            bf16x8 pf = ks ? pf1 : pf0;
            o0 = __builtin_amdgcn_mfma_f32_32x32x16_bf16(v0, pf, o0, 0, 0, 0);
            o1 = __builtin_amdgcn_mfma_f32_32x32x16_bf16(v1, pf, o1, 0, 0, 0);
        }
        __builtin_amdgcn_s_setprio(0);
    };

    // prologue: tile 0 -> buf0; tile 1 -> regs
    stage(0);
    writeb(k0b, v0b);
    stage(64);
    __syncthreads();

    for (int t = 0; t < 32; t += 2) {
        // even iter: compute buf0, regs hold tile t+1 -> buf1
        writeb(k1b, v1b);
        if (t + 2 < 32) stage((t + 2) * 64);
        compute(k0b, v0b, t * 64);
        __syncthreads();
        // odd iter: compute buf1, regs hold tile t+2 -> buf0
        if (t + 2 < 32) {
            writeb(k0b, v0b);
            if (t + 3 < 32) stage((t + 3) * 64);
        }
        compute(k1b, v1b, (t + 1) * 64);
        __syncthreads();
    }

    // ---- epilogue: merge jp partials via LDS, normalize, direct 16B stores ----
    float lt = lloc + __shfl_xor(lloc, 32, 64);  // combine hi halves (same q)
    float* sM = (float*)smem;                    // aliases KV buffers (loop done)
    const int key = (lane & 7) << 2;
    if (jp == 1) {
        float* dst = sM + qh * 2048 + lane * 32;
#pragma unroll
        for (int i = 0; i < 4; ++i) {
            f32x4 t0 = {o0[4 * i], o0[4 * i + 1], o0[4 * i + 2], o0[4 * i + 3]};
            f32x4 t1 = {o1[4 * i], o1[4 * i + 1], o1[4 * i + 2], o1[4 * i + 3]};
            *reinterpret_cast<f32x4*>(dst + ((4 * i) ^ key))      = t0;
            *reinterpret_cast<f32x4*>(dst + ((16 + 4 * i) ^ key)) = t1;
        }
        sMl[qh * 64 + lane] = lt;
    }
    __syncthreads();
    if (jp == 0) {
        const float* src = sM + qh * 2048 + lane * 32;
#pragma unroll
        for (int i = 0; i < 4; ++i) {
            f32x4 t0 = *reinterpret_cast<const f32x4*>(src + ((4 * i) ^ key));
            f32x4 t1 = *reinterpret_cast<const f32x4*>(src + ((16 + 4 * i) ^ key));
#pragma unroll
            for (int r = 0; r < 4; ++r) { o0[4 * i + r] += t0[r]; o1[4 * i + r] += t1[r]; }
        }
        const float linv = 1.0f / (lt + sMl[qh * 64 + lane]);
        float* orow = &Out[(rowbase + q0 + l31) * 512 + hc];
#pragma unroll
        for (int t = 0; t < 4; ++t) {
            f32x4 a, c;
#pragma unroll
            for (int r = 0; r < 4; ++r) {
                a[r] = o0[4 * t + r] * linv;
                c[r] = o1[4 * t + r] * linv;
            }
            *reinterpret_cast<f32x4*>(orow + 8 * t + 4 * hi)      = a;
            *reinterpret_cast<f32x4*>(orow + 32 + 8 * t + 4 * hi) = c;
        }
    }
}

extern "C" void kernel_launch(void* const* d_in, const int* in_sizes, int n_in,
                              void* d_out, int out_size, void* d_ws, size_t ws_size,
                              hipStream_t stream) {
    const float* x   = (const float*)d_in[0];
    const float* pos = (const float*)d_in[1];
    const float* Wq  = (const float*)d_in[2];
    const float* Wk  = (const float*)d_in[3];
    float* out = (float*)d_out;

    // ws (bf16 elems): Q 4.19M | K 4.19M | Vt 4.19M  (~25MB)
    unsigned short* Qb  = (unsigned short*)d_ws;
    unsigned short* Kbf = Qb  + 4194304;
    unsigned short* Vtb = Kbf + 4194304;

    gemm_qk<<<dim3(768), dim3(256), 0, stream>>>(x, Wq, Wk, Qb, Kbf, Vtb);
    attn_fwd<<<dim3(512), dim3(512), 0, stream>>>(Qb, Kbf, Vtb, pos, out);
}

// Round 19
// 80.179 us; speedup vs baseline: 1.0137x; 1.0137x over previous
//
#include <hip/hip_runtime.h>
#include <hip/hip_bf16.h>

typedef __bf16 bf16x8 __attribute__((ext_vector_type(8)));
typedef float f32x4 __attribute__((ext_vector_type(4)));
typedef float f32x16 __attribute__((ext_vector_type(16)));

__device__ inline unsigned short f2bf(float f) {
    __hip_bfloat16 h = __float2bfloat16(f);
    return __builtin_bit_cast(unsigned short, h);
}
__device__ inline unsigned pk2bf(float a, float b) {
    return (unsigned)f2bf(a) | ((unsigned)f2bf(b) << 16);
}
__device__ inline float exp2_fast(float x) {
    float r;
    asm("v_exp_f32 %0, %1" : "=v"(r) : "v"(x));
    return r;
}

#define QSCALE 0.1803368801111244f  /* 0.125 * log2(e) */

// ------- fused projection + V-transpose: grid (64, 12) x 256 threads -----------------
// by 0..3:  Q = (x Wq^T) * QSCALE   (128x128 GEMM tile)
// by 4..7:  K = x Wk^T
// by 8..11: V transpose slice: x[b][n][hc+d] -> Vt[b*8+h][d][n'] for h = 2(by-8)+{0,1}.
//           n' = bit2<->bit3 permuted within 16-block (PV fragment contiguous 16B).
__global__ __launch_bounds__(256) void gemm_qk(const float* __restrict__ x,
                                               const float* __restrict__ Wq,
                                               const float* __restrict__ Wk,
                                               unsigned short* __restrict__ Qb,
                                               unsigned short* __restrict__ Kb,
                                               unsigned short* __restrict__ Vt) {
    __shared__ __align__(16) unsigned short sA[128 * 40];
    __shared__ __align__(16) unsigned short sB[128 * 40];
    const int tid  = threadIdx.x;
    const int by = blockIdx.y;

    if (by >= 8) {  // ---- V transpose slice ----
        const int q = by - 8;
        const int nl = tid & 127, hh = tid >> 7;
        const int h = q * 2 + hh;
        const int g = blockIdx.x * 128 + nl;       // global row 0..8191
        const int b = g >> 11, n = g & 2047;
        const int np = (n & ~15) | (n & 3) | ((n & 4) << 1) | ((n & 8) >> 1);
        const size_t xrow = ((size_t)b * 2048 + n) * 512 + h * 64;
        const size_t vbase = ((size_t)(b * 8 + h) * 64) * 2048 + np;
#pragma unroll
        for (int d0 = 0; d0 < 64; d0 += 4) {
            float4 v = *reinterpret_cast<const float4*>(&x[xrow + d0]);
            Vt[vbase + (size_t)(d0 + 0) * 2048] = f2bf(v.x);
            Vt[vbase + (size_t)(d0 + 1) * 2048] = f2bf(v.y);
            Vt[vbase + (size_t)(d0 + 2) * 2048] = f2bf(v.z);
            Vt[vbase + (size_t)(d0 + 3) * 2048] = f2bf(v.w);
        }
        return;
    }

    const int lane = tid & 63;
    const int wave = tid >> 6;
    const int wr = wave >> 1, wc = wave & 1;
    const int bm = blockIdx.x * 128;
    const float* __restrict__ Bsrc = (by < 4) ? Wq : Wk;
    unsigned short* __restrict__ C = (by < 4) ? Qb : Kb;
    const int bn = (by & 3) * 128;
    const float scale = (by < 4) ? QSCALE : 1.0f;
    const int tr = tid >> 1, th = (tid & 1) * 16;
    const int rl = lane & 15;
    const int kq = (lane >> 4) * 8;

    f32x4 acc[4][4];
#pragma unroll
    for (int m = 0; m < 4; ++m)
#pragma unroll
        for (int n = 0; n < 4; ++n) acc[m][n] = (f32x4){0.f, 0.f, 0.f, 0.f};

    for (int k0 = 0; k0 < 512; k0 += 32) {
        const float* ap = &x[(size_t)(bm + tr) * 512 + k0 + th];
        const float* bp = &Bsrc[(size_t)(bn + tr) * 512 + k0 + th];
        float4 a0 = *reinterpret_cast<const float4*>(ap);
        float4 a1 = *reinterpret_cast<const float4*>(ap + 4);
        float4 a2 = *reinterpret_cast<const float4*>(ap + 8);
        float4 a3 = *reinterpret_cast<const float4*>(ap + 12);
        float4 b0 = *reinterpret_cast<const float4*>(bp);
        float4 b1 = *reinterpret_cast<const float4*>(bp + 4);
        float4 b2 = *reinterpret_cast<const float4*>(bp + 8);
        float4 b3 = *reinterpret_cast<const float4*>(bp + 12);
        uint4 pa0 = {pk2bf(a0.x, a0.y), pk2bf(a0.z, a0.w), pk2bf(a1.x, a1.y), pk2bf(a1.z, a1.w)};
        uint4 pa1 = {pk2bf(a2.x, a2.y), pk2bf(a2.z, a2.w), pk2bf(a3.x, a3.y), pk2bf(a3.z, a3.w)};
        uint4 pb0 = {pk2bf(b0.x, b0.y), pk2bf(b0.z, b0.w), pk2bf(b1.x, b1.y), pk2bf(b1.z, b1.w)};
        uint4 pb1 = {pk2bf(b2.x, b2.y), pk2bf(b2.z, b2.w), pk2bf(b3.x, b3.y), pk2bf(b3.z, b3.w)};
        __syncthreads();
        *reinterpret_cast<uint4*>(&sA[tr * 40 + th])     = pa0;
        *reinterpret_cast<uint4*>(&sA[tr * 40 + th + 8]) = pa1;
        *reinterpret_cast<uint4*>(&sB[tr * 40 + th])     = pb0;
        *reinterpret_cast<uint4*>(&sB[tr * 40 + th + 8]) = pb1;
        __syncthreads();

        bf16x8 af[4], bfv[4];
#pragma unroll
        for (int m = 0; m < 4; ++m)
            af[m] = __builtin_bit_cast(bf16x8,
                *reinterpret_cast<const uint4*>(&sA[(wr * 64 + m * 16 + rl) * 40 + kq]));
#pragma unroll
        for (int n = 0; n < 4; ++n)
            bfv[n] = __builtin_bit_cast(bf16x8,
                *reinterpret_cast<const uint4*>(&sB[(wc * 64 + n * 16 + rl) * 40 + kq]));
#pragma unroll
        for (int m = 0; m < 4; ++m)
#pragma unroll
            for (int n = 0; n < 4; ++n)
                acc[m][n] = __builtin_amdgcn_mfma_f32_16x16x32_bf16(af[m], bfv[n], acc[m][n], 0, 0, 0);
    }

    const int rq = (lane >> 4) * 4;
#pragma unroll
    for (int m = 0; m < 4; ++m) {
        int r = bm + wr * 64 + m * 16 + rq;
#pragma unroll
        for (int n = 0; n < 4; ++n) {
            int c = bn + wc * 64 + n * 16 + rl;
#pragma unroll
            for (int reg = 0; reg < 4; ++reg)
                C[(size_t)(r + reg) * 512 + c] = f2bf(acc[m][n][reg] * scale);
        }
    }
}

// ---------------- fused flash attention: 8 waves (4qh x 2jp), dbuf, 1 barrier/tile ---
// grid: 512 flat blocks, XCD bh-affinity (xcd=flat&7 owns bh {4xcd..4xcd+3}) -> per-XCD
// K/V working set 2MB, L2-resident. block: 512 = 8 waves; wave: qh=w&3, jp=w>>2.
// Fixed-reference softmax in log2 domain (log2e folded into Q-scale and slope).
// One-time sPos table (slopeL*pos, 8KB LDS) removes pos staging from the loop.
// NO s_setprio (round-19: m190 analog — lockstep barrier-synced waves, setprio never
// isolated-positive here; removed for A/B).
// S^T: mfma(K,Q) -> D[row=j][col=q]: lane q=l31, j=(r&3)+8*(r>>2)+4*hi.
// PV: P-frag lane-local, j-map = 16ks + 4hi + (e&3) + 8*(e>>2); V pre-permuted so this
// fragment is one contiguous b128 read. LDS rows XOR-swizzled (byte ^= (row&7)<<4).
__global__ __launch_bounds__(512, 4) void attn_fwd(const unsigned short* __restrict__ Q,
                                                   const unsigned short* __restrict__ Kb,
                                                   const unsigned short* __restrict__ Vt,
                                                   const float* __restrict__ pos,
                                                   float* __restrict__ Out) {
    __shared__ __align__(16) unsigned char smem[42240];
    char* k0b = (char*)smem;                 // 8 KiB
    char* v0b = (char*)smem + 8192;          // 8 KiB
    char* k1b = (char*)smem + 16384;         // 8 KiB
    char* v1b = (char*)smem + 24576;         // 8 KiB
    float* sPosT = (float*)(smem + 32768);   // 2048 f32 slopeL*pos (8 KiB)
    float* sMl   = (float*)(smem + 40960);   // 256 f32 (epilogue l merge)

    const int tid  = threadIdx.x;
    const int lane = tid & 63;
    const int w    = tid >> 6;
    const int l31  = lane & 31;
    const int hi   = lane >> 5;
    const int qh   = w & 3;
    const int jp   = w >> 2;
    // XCD-affine decode (512 blocks, bijective: 512 % 8 == 0)
    const int flat = blockIdx.x;
    const int xcd  = flat & 7;
    const int idx  = flat >> 3;              // 0..63
    const int bh   = xcd * 4 + (idx >> 4);
    const int qt   = idx & 15;
    const int b = bh >> 3, h = bh & 7;
    const int q0 = qt * 128 + qh * 32;
    const size_t rowbase = (size_t)b * 2048;
    const int hc = h * 64;
    const float slopeL = ldexpf(1.4426950408889634f, -(h + 1));  // slope * log2(e)

    // Q B-fragments: lane supplies Q[q=l31][c = ks*16 + hi*8 + e] (Q pre-scaled)
    bf16x8 qf0, qf1, qf2, qf3;
    {
        const unsigned short* qp = &Q[(rowbase + q0 + l31) * 512 + hc + hi * 8];
        qf0 = __builtin_bit_cast(bf16x8, *reinterpret_cast<const uint4*>(qp));
        qf1 = __builtin_bit_cast(bf16x8, *reinterpret_cast<const uint4*>(qp + 16));
        qf2 = __builtin_bit_cast(bf16x8, *reinterpret_cast<const uint4*>(qp + 32));
        qf3 = __builtin_bit_cast(bf16x8, *reinterpret_cast<const uint4*>(qp + 48));
    }
    const float ui = slopeL * pos[rowbase + q0 + l31];

    // one-time slopeL*pos table (512 threads x 4 = 2048)
    {
        float4 v = reinterpret_cast<const float4*>(pos + rowbase)[tid];
        reinterpret_cast<f32x4*>(sPosT)[tid] =
            (f32x4){v.x * slopeL, v.y * slopeL, v.z * slopeL, v.w * slopeL};
    }

    float lloc = 0.f;
    f32x16 o0, o1;
#pragma unroll
    for (int r = 0; r < 16; ++r) { o0[r] = 0.f; o1[r] = 0.f; }

    // staging: 8 threads/row x 16 B; write slot XOR-swizzled -> conflict-free
    const int sr  = tid >> 3;                       // row 0..63
    const int sce = (tid & 7) * 8;                  // elem col (8 elems/thread)
    const int wbyte = sr * 128 + (((tid & 7) * 16) ^ ((sr & 7) << 4));
    const int kswz = (l31 & 7) << 4;                // compute-side swizzle key

    uint4 ck, cv;

    auto stage = [&](int j0v) {
        ck = *reinterpret_cast<const uint4*>(&Kb[(rowbase + j0v + sr) * 512 + hc + sce]);
        cv = *reinterpret_cast<const uint4*>(&Vt[((size_t)bh * 64 + sr) * 2048 + j0v + sce]);
    };
    auto writeb = [&](char* KB, char* VB) {
        *reinterpret_cast<uint4*>(KB + wbyte) = ck;
        *reinterpret_cast<uint4*>(VB + wbyte) = cv;
    };
    auto compute = [&](const char* KB, const char* VB, int j0) {
        const char* kr = KB + (32 * jp + l31) * 128;
        // ---- S chunk (32j x 32q) for this wave's (qh, jp) ----
        f32x16 s;
#pragma unroll
        for (int r = 0; r < 16; ++r) s[r] = 0.f;
#pragma unroll
        for (int ks = 0; ks < 4; ++ks) {
            bf16x8 kf = __builtin_bit_cast(bf16x8,
                *reinterpret_cast<const uint4*>(kr + ((ks * 32 + hi * 16) ^ kswz)));
            bf16x8 qq = (ks == 0) ? qf0 : (ks == 1) ? qf1 : (ks == 2) ? qf2 : qf3;
            s = __builtin_amdgcn_mfma_f32_32x32x16_bf16(kf, qq, s, 0, 0, 0);
        }

        // ---- bias + exp2 (fixed reference, log2 domain) ----
        float ls = 0.f;
#pragma unroll
        for (int t = 0; t < 4; ++t) {
            f32x4 u = *reinterpret_cast<const f32x4*>(&sPosT[j0 + 32 * jp + 8 * t + 4 * hi]);
#pragma unroll
            for (int r = 0; r < 4; ++r) {
                float p = exp2_fast(s[4 * t + r] - fabsf(u[r] - ui));
                s[4 * t + r] = p;
                ls += p;
            }
        }
        lloc += ls;

        // ---- lane-local P fragments (j = 16ks + 4hi + (e&3) + 8*(e>>2)) ----
        bf16x8 pf0 = __builtin_bit_cast(bf16x8, (uint4){
            pk2bf(s[0], s[1]),  pk2bf(s[2], s[3]),   pk2bf(s[4], s[5]),   pk2bf(s[6], s[7])});
        bf16x8 pf1 = __builtin_bit_cast(bf16x8, (uint4){
            pk2bf(s[8], s[9]),  pk2bf(s[10], s[11]), pk2bf(s[12], s[13]), pk2bf(s[14], s[15])});

        // ---- PV: O^T[d][q] += V-frag x P-frag; V pre-permuted -> single b128/frag ----
        const char* vr0 = VB + l31 * 128;
        const char* vr1 = VB + (32 + l31) * 128;
#pragma unroll
        for (int ks = 0; ks < 2; ++ks) {
            const int cb = (64 * jp + ks * 32 + hi * 16) ^ kswz;  // permuted-stored
            bf16x8 v0 = __builtin_bit_cast(bf16x8, *reinterpret_cast<const uint4*>(vr0 + cb));
            bf16x8 v1 = __builtin_bit_cast(bf16x8, *reinterpret_cast<const uint4*>(vr1 + cb));
            bf16x8 pf = ks ? pf1 : pf0;
            o0 = __builtin_amdgcn_mfma_f32_32x32x16_bf16(v0, pf, o0, 0, 0, 0);
            o1 = __builtin_amdgcn_mfma_f32_32x32x16_bf16(v1, pf, o1, 0, 0, 0);
        }
    };

    // prologue: tile 0 -> buf0; tile 1 -> regs
    stage(0);
    writeb(k0b, v0b);
    stage(64);
    __syncthreads();

    for (int t = 0; t < 32; t += 2) {
        // even iter: compute buf0, regs hold tile t+1 -> buf1
        writeb(k1b, v1b);
        if (t + 2 < 32) stage((t + 2) * 64);
        compute(k0b, v0b, t * 64);
        __syncthreads();
        // odd iter: compute buf1, regs hold tile t+2 -> buf0
        if (t + 2 < 32) {
            writeb(k0b, v0b);
            if (t + 3 < 32) stage((t + 3) * 64);
        }
        compute(k1b, v1b, (t + 1) * 64);
        __syncthreads();
    }

    // ---- epilogue: merge jp partials via LDS, normalize, direct 16B stores ----
    float lt = lloc + __shfl_xor(lloc, 32, 64);  // combine hi halves (same q)
    float* sM = (float*)smem;                    // aliases KV buffers (loop done)
    const int key = (lane & 7) << 2;
    if (jp == 1) {
        float* dst = sM + qh * 2048 + lane * 32;
#pragma unroll
        for (int i = 0; i < 4; ++i) {
            f32x4 t0 = {o0[4 * i], o0[4 * i + 1], o0[4 * i + 2], o0[4 * i + 3]};
            f32x4 t1 = {o1[4 * i], o1[4 * i + 1], o1[4 * i + 2], o1[4 * i + 3]};
            *reinterpret_cast<f32x4*>(dst + ((4 * i) ^ key))      = t0;
            *reinterpret_cast<f32x4*>(dst + ((16 + 4 * i) ^ key)) = t1;
        }
        sMl[qh * 64 + lane] = lt;
    }
    __syncthreads();
    if (jp == 0) {
        const float* src = sM + qh * 2048 + lane * 32;
#pragma unroll
        for (int i = 0; i < 4; ++i) {
            f32x4 t0 = *reinterpret_cast<const f32x4*>(src + ((4 * i) ^ key));
            f32x4 t1 = *reinterpret_cast<const f32x4*>(src + ((16 + 4 * i) ^ key));
#pragma unroll
            for (int r = 0; r < 4; ++r) { o0[4 * i + r] += t0[r]; o1[4 * i + r] += t1[r]; }
        }
        const float linv = 1.0f / (lt + sMl[qh * 64 + lane]);
        float* orow = &Out[(rowbase + q0 + l31) * 512 + hc];
#pragma unroll
        for (int t = 0; t < 4; ++t) {
            f32x4 a, c;
#pragma unroll
            for (int r = 0; r < 4; ++r) {
                a[r] = o0[4 * t + r] * linv;
                c[r] = o1[4 * t + r] * linv;
            }
            *reinterpret_cast<f32x4*>(orow + 8 * t + 4 * hi)      = a;
            *reinterpret_cast<f32x4*>(orow + 32 + 8 * t + 4 * hi) = c;
        }
    }
}

extern "C" void kernel_launch(void* const* d_in, const int* in_sizes, int n_in,
                              void* d_out, int out_size, void* d_ws, size_t ws_size,
                              hipStream_t stream) {
    const float* x   = (const float*)d_in[0];
    const float* pos = (const float*)d_in[1];
    const float* Wq  = (const float*)d_in[2];
    const float* Wk  = (const float*)d_in[3];
    float* out = (float*)d_out;

    // ws (bf16 elems): Q 4.19M | K 4.19M | Vt 4.19M  (~25MB)
    unsigned short* Qb  = (unsigned short*)d_ws;
    unsigned short* Kbf = Qb  + 4194304;
    unsigned short* Vtb = Kbf + 4194304;

    gemm_qk<<<dim3(64, 12), dim3(256), 0, stream>>>(x, Wq, Wk, Qb, Kbf, Vtb);
    attn_fwd<<<dim3(512), dim3(512), 0, stream>>>(Qb, Kbf, Vtb, pos, out);
}

// Round 20
// 76.488 us; speedup vs baseline: 1.0626x; 1.0483x over previous
//
#include <hip/hip_runtime.h>
#include <hip/hip_bf16.h>

typedef __bf16 bf16x8 __attribute__((ext_vector_type(8)));
typedef float f32x4 __attribute__((ext_vector_type(4)));
typedef float f32x16 __attribute__((ext_vector_type(16)));

__device__ inline unsigned short f2bf(float f) {
    __hip_bfloat16 h = __float2bfloat16(f);
    return __builtin_bit_cast(unsigned short, h);
}
__device__ inline unsigned pk2bf(float a, float b) {
    return (unsigned)f2bf(a) | ((unsigned)f2bf(b) << 16);
}
// truncation-pack: dst = {hi16(lo), hi16(hi)} via single v_perm_b32 (bytes {2,3,6,7}
// of the {src1,src0} pool). P in [0,1] -> truncation error < 2^-8 relative, negligible.
__device__ inline unsigned pkhi(float lo, float hi) {
    return __builtin_amdgcn_perm(__builtin_bit_cast(unsigned, hi),
                                 __builtin_bit_cast(unsigned, lo), 0x07060302u);
}
__device__ inline float exp2_fast(float x) {
    float r;
    asm("v_exp_f32 %0, %1" : "=v"(r) : "v"(x));
    return r;
}

#define QSCALE 0.1803368801111244f  /* 0.125 * log2(e) */

// ------- fused projection + V-transpose: grid (64, 12) x 256 threads -----------------
// by 0..3:  Q = (x Wq^T) * QSCALE   (128x128 GEMM tile)
// by 4..7:  K = x Wk^T
// by 8..11: V transpose slice: x[b][n][hc+d] -> Vt[b*8+h][d][n'] for h = 2(by-8)+{0,1}.
//           n' = bit2<->bit3 permuted within 16-block (PV fragment contiguous 16B).
__global__ __launch_bounds__(256) void gemm_qk(const float* __restrict__ x,
                                               const float* __restrict__ Wq,
                                               const float* __restrict__ Wk,
                                               unsigned short* __restrict__ Qb,
                                               unsigned short* __restrict__ Kb,
                                               unsigned short* __restrict__ Vt) {
    __shared__ __align__(16) unsigned short sA[128 * 40];
    __shared__ __align__(16) unsigned short sB[128 * 40];
    const int tid  = threadIdx.x;
    const int by = blockIdx.y;

    if (by >= 8) {  // ---- V transpose slice ----
        const int q = by - 8;
        const int nl = tid & 127, hh = tid >> 7;
        const int h = q * 2 + hh;
        const int g = blockIdx.x * 128 + nl;       // global row 0..8191
        const int b = g >> 11, n = g & 2047;
        const int np = (n & ~15) | (n & 3) | ((n & 4) << 1) | ((n & 8) >> 1);
        const size_t xrow = ((size_t)b * 2048 + n) * 512 + h * 64;
        const size_t vbase = ((size_t)(b * 8 + h) * 64) * 2048 + np;
#pragma unroll
        for (int d0 = 0; d0 < 64; d0 += 4) {
            float4 v = *reinterpret_cast<const float4*>(&x[xrow + d0]);
            Vt[vbase + (size_t)(d0 + 0) * 2048] = f2bf(v.x);
            Vt[vbase + (size_t)(d0 + 1) * 2048] = f2bf(v.y);
            Vt[vbase + (size_t)(d0 + 2) * 2048] = f2bf(v.z);
            Vt[vbase + (size_t)(d0 + 3) * 2048] = f2bf(v.w);
        }
        return;
    }

    const int lane = tid & 63;
    const int wave = tid >> 6;
    const int wr = wave >> 1, wc = wave & 1;
    const int bm = blockIdx.x * 128;
    const float* __restrict__ Bsrc = (by < 4) ? Wq : Wk;
    unsigned short* __restrict__ C = (by < 4) ? Qb : Kb;
    const int bn = (by & 3) * 128;
    const float scale = (by < 4) ? QSCALE : 1.0f;
    const int tr = tid >> 1, th = (tid & 1) * 16;
    const int rl = lane & 15;
    const int kq = (lane >> 4) * 8;

    f32x4 acc[4][4];
#pragma unroll
    for (int m = 0; m < 4; ++m)
#pragma unroll
        for (int n = 0; n < 4; ++n) acc[m][n] = (f32x4){0.f, 0.f, 0.f, 0.f};

    for (int k0 = 0; k0 < 512; k0 += 32) {
        const float* ap = &x[(size_t)(bm + tr) * 512 + k0 + th];
        const float* bp = &Bsrc[(size_t)(bn + tr) * 512 + k0 + th];
        float4 a0 = *reinterpret_cast<const float4*>(ap);
        float4 a1 = *reinterpret_cast<const float4*>(ap + 4);
        float4 a2 = *reinterpret_cast<const float4*>(ap + 8);
        float4 a3 = *reinterpret_cast<const float4*>(ap + 12);
        float4 b0 = *reinterpret_cast<const float4*>(bp);
        float4 b1 = *reinterpret_cast<const float4*>(bp + 4);
        float4 b2 = *reinterpret_cast<const float4*>(bp + 8);
        float4 b3 = *reinterpret_cast<const float4*>(bp + 12);
        uint4 pa0 = {pk2bf(a0.x, a0.y), pk2bf(a0.z, a0.w), pk2bf(a1.x, a1.y), pk2bf(a1.z, a1.w)};
        uint4 pa1 = {pk2bf(a2.x, a2.y), pk2bf(a2.z, a2.w), pk2bf(a3.x, a3.y), pk2bf(a3.z, a3.w)};
        uint4 pb0 = {pk2bf(b0.x, b0.y), pk2bf(b0.z, b0.w), pk2bf(b1.x, b1.y), pk2bf(b1.z, b1.w)};
        uint4 pb1 = {pk2bf(b2.x, b2.y), pk2bf(b2.z, b2.w), pk2bf(b3.x, b3.y), pk2bf(b3.z, b3.w)};
        __syncthreads();
        *reinterpret_cast<uint4*>(&sA[tr * 40 + th])     = pa0;
        *reinterpret_cast<uint4*>(&sA[tr * 40 + th + 8]) = pa1;
        *reinterpret_cast<uint4*>(&sB[tr * 40 + th])     = pb0;
        *reinterpret_cast<uint4*>(&sB[tr * 40 + th + 8]) = pb1;
        __syncthreads();

        bf16x8 af[4], bfv[4];
#pragma unroll
        for (int m = 0; m < 4; ++m)
            af[m] = __builtin_bit_cast(bf16x8,
                *reinterpret_cast<const uint4*>(&sA[(wr * 64 + m * 16 + rl) * 40 + kq]));
#pragma unroll
        for (int n = 0; n < 4; ++n)
            bfv[n] = __builtin_bit_cast(bf16x8,
                *reinterpret_cast<const uint4*>(&sB[(wc * 64 + n * 16 + rl) * 40 + kq]));
#pragma unroll
        for (int m = 0; m < 4; ++m)
#pragma unroll
            for (int n = 0; n < 4; ++n)
                acc[m][n] = __builtin_amdgcn_mfma_f32_16x16x32_bf16(af[m], bfv[n], acc[m][n], 0, 0, 0);
    }

    const int rq = (lane >> 4) * 4;
#pragma unroll
    for (int m = 0; m < 4; ++m) {
        int r = bm + wr * 64 + m * 16 + rq;
#pragma unroll
        for (int n = 0; n < 4; ++n) {
            int c = bn + wc * 64 + n * 16 + rl;
#pragma unroll
            for (int reg = 0; reg < 4; ++reg)
                C[(size_t)(r + reg) * 512 + c] = f2bf(acc[m][n][reg] * scale);
        }
    }
}

// ---------------- fused flash attention: 8 waves (4qh x 2jp), dbuf, 1 barrier/tile ---
// grid: 512 flat blocks, XCD bh-affinity (xcd=flat&7 owns bh {4xcd..4xcd+3}) -> per-XCD
// K/V working set 2MB, L2-resident. block: 512 = 8 waves; wave: qh=w&3, jp=w>>2.
// Fixed-reference softmax in log2 domain (log2e folded into Q-scale and slope).
// One-time sPos table (slopeL*pos, 8KB LDS) removes pos staging from the loop.
// P-pack via single v_perm_b32 truncation per pair (round-20: replaces RNE cvt chain).
// S^T: mfma(K,Q) -> D[row=j][col=q]: lane q=l31, j=(r&3)+8*(r>>2)+4*hi.
// PV: P-frag lane-local, j-map = 16ks + 4hi + (e&3) + 8*(e>>2); V pre-permuted so this
// fragment is one contiguous b128 read. LDS rows XOR-swizzled (byte ^= (row&7)<<4).
__global__ __launch_bounds__(512, 4) void attn_fwd(const unsigned short* __restrict__ Q,
                                                   const unsigned short* __restrict__ Kb,
                                                   const unsigned short* __restrict__ Vt,
                                                   const float* __restrict__ pos,
                                                   float* __restrict__ Out) {
    __shared__ __align__(16) unsigned char smem[42240];
    char* k0b = (char*)smem;                 // 8 KiB
    char* v0b = (char*)smem + 8192;          // 8 KiB
    char* k1b = (char*)smem + 16384;         // 8 KiB
    char* v1b = (char*)smem + 24576;         // 8 KiB
    float* sPosT = (float*)(smem + 32768);   // 2048 f32 slopeL*pos (8 KiB)
    float* sMl   = (float*)(smem + 40960);   // 256 f32 (epilogue l merge)

    const int tid  = threadIdx.x;
    const int lane = tid & 63;
    const int w    = tid >> 6;
    const int l31  = lane & 31;
    const int hi   = lane >> 5;
    const int qh   = w & 3;
    const int jp   = w >> 2;
    // XCD-affine decode (512 blocks, bijective: 512 % 8 == 0)
    const int flat = blockIdx.x;
    const int xcd  = flat & 7;
    const int idx  = flat >> 3;              // 0..63
    const int bh   = xcd * 4 + (idx >> 4);
    const int qt   = idx & 15;
    const int b = bh >> 3, h = bh & 7;
    const int q0 = qt * 128 + qh * 32;
    const size_t rowbase = (size_t)b * 2048;
    const int hc = h * 64;
    const float slopeL = ldexpf(1.4426950408889634f, -(h + 1));  // slope * log2(e)

    // Q B-fragments: lane supplies Q[q=l31][c = ks*16 + hi*8 + e] (Q pre-scaled)
    bf16x8 qf0, qf1, qf2, qf3;
    {
        const unsigned short* qp = &Q[(rowbase + q0 + l31) * 512 + hc + hi * 8];
        qf0 = __builtin_bit_cast(bf16x8, *reinterpret_cast<const uint4*>(qp));
        qf1 = __builtin_bit_cast(bf16x8, *reinterpret_cast<const uint4*>(qp + 16));
        qf2 = __builtin_bit_cast(bf16x8, *reinterpret_cast<const uint4*>(qp + 32));
        qf3 = __builtin_bit_cast(bf16x8, *reinterpret_cast<const uint4*>(qp + 48));
    }
    const float ui = slopeL * pos[rowbase + q0 + l31];

    // one-time slopeL*pos table (512 threads x 4 = 2048)
    {
        float4 v = reinterpret_cast<const float4*>(pos + rowbase)[tid];
        reinterpret_cast<f32x4*>(sPosT)[tid] =
            (f32x4){v.x * slopeL, v.y * slopeL, v.z * slopeL, v.w * slopeL};
    }

    float lloc = 0.f;
    f32x16 o0, o1;
#pragma unroll
    for (int r = 0; r < 16; ++r) { o0[r] = 0.f; o1[r] = 0.f; }

    // staging: 8 threads/row x 16 B; write slot XOR-swizzled -> conflict-free
    const int sr  = tid >> 3;                       // row 0..63
    const int sce = (tid & 7) * 8;                  // elem col (8 elems/thread)
    const int wbyte = sr * 128 + (((tid & 7) * 16) ^ ((sr & 7) << 4));
    const int kswz = (l31 & 7) << 4;                // compute-side swizzle key

    uint4 ck, cv;

    auto stage = [&](int j0v) {
        ck = *reinterpret_cast<const uint4*>(&Kb[(rowbase + j0v + sr) * 512 + hc + sce]);
        cv = *reinterpret_cast<const uint4*>(&Vt[((size_t)bh * 64 + sr) * 2048 + j0v + sce]);
    };
    auto writeb = [&](char* KB, char* VB) {
        *reinterpret_cast<uint4*>(KB + wbyte) = ck;
        *reinterpret_cast<uint4*>(VB + wbyte) = cv;
    };
    auto compute = [&](const char* KB, const char* VB, int j0) {
        const char* kr = KB + (32 * jp + l31) * 128;
        // ---- S chunk (32j x 32q) for this wave's (qh, jp) ----
        f32x16 s;
#pragma unroll
        for (int r = 0; r < 16; ++r) s[r] = 0.f;
        __builtin_amdgcn_s_setprio(1);
#pragma unroll
        for (int ks = 0; ks < 4; ++ks) {
            bf16x8 kf = __builtin_bit_cast(bf16x8,
                *reinterpret_cast<const uint4*>(kr + ((ks * 32 + hi * 16) ^ kswz)));
            bf16x8 qq = (ks == 0) ? qf0 : (ks == 1) ? qf1 : (ks == 2) ? qf2 : qf3;
            s = __builtin_amdgcn_mfma_f32_32x32x16_bf16(kf, qq, s, 0, 0, 0);
        }
        __builtin_amdgcn_s_setprio(0);

        // ---- bias + exp2 (fixed reference, log2 domain) ----
        float ls = 0.f;
#pragma unroll
        for (int t = 0; t < 4; ++t) {
            f32x4 u = *reinterpret_cast<const f32x4*>(&sPosT[j0 + 32 * jp + 8 * t + 4 * hi]);
#pragma unroll
            for (int r = 0; r < 4; ++r) {
                float p = exp2_fast(s[4 * t + r] - fabsf(u[r] - ui));
                s[4 * t + r] = p;
                ls += p;
            }
        }
        lloc += ls;

        // ---- lane-local P fragments (j = 16ks + 4hi + (e&3) + 8*(e>>2)) ----
        // single-instruction truncation pack per bf16 pair (v_perm_b32)
        bf16x8 pf0 = __builtin_bit_cast(bf16x8, (uint4){
            pkhi(s[0], s[1]),  pkhi(s[2], s[3]),   pkhi(s[4], s[5]),   pkhi(s[6], s[7])});
        bf16x8 pf1 = __builtin_bit_cast(bf16x8, (uint4){
            pkhi(s[8], s[9]),  pkhi(s[10], s[11]), pkhi(s[12], s[13]), pkhi(s[14], s[15])});

        // ---- PV: O^T[d][q] += V-frag x P-frag; V pre-permuted -> single b128/frag ----
        const char* vr0 = VB + l31 * 128;
        const char* vr1 = VB + (32 + l31) * 128;
        __builtin_amdgcn_s_setprio(1);
#pragma unroll
        for (int ks = 0; ks < 2; ++ks) {
            const int cb = (64 * jp + ks * 32 + hi * 16) ^ kswz;  // permuted-stored
            bf16x8 v0 = __builtin_bit_cast(bf16x8, *reinterpret_cast<const uint4*>(vr0 + cb));
            bf16x8 v1 = __builtin_bit_cast(bf16x8, *reinterpret_cast<const uint4*>(vr1 + cb));
            bf16x8 pf = ks ? pf1 : pf0;
            o0 = __builtin_amdgcn_mfma_f32_32x32x16_bf16(v0, pf, o0, 0, 0, 0);
            o1 = __builtin_amdgcn_mfma_f32_32x32x16_bf16(v1, pf, o1, 0, 0, 0);
        }
        __builtin_amdgcn_s_setprio(0);
    };

    // prologue: tile 0 -> buf0; tile 1 -> regs
    stage(0);
    writeb(k0b, v0b);
    stage(64);
    __syncthreads();

    for (int t = 0; t < 32; t += 2) {
        // even iter: compute buf0, regs hold tile t+1 -> buf1
        writeb(k1b, v1b);
        if (t + 2 < 32) stage((t + 2) * 64);
        compute(k0b, v0b, t * 64);
        __syncthreads();
        // odd iter: compute buf1, regs hold tile t+2 -> buf0
        if (t + 2 < 32) {
            writeb(k0b, v0b);
            if (t + 3 < 32) stage((t + 3) * 64);
        }
        compute(k1b, v1b, (t + 1) * 64);
        __syncthreads();
    }

    // ---- epilogue: merge jp partials via LDS, normalize, direct 16B stores ----
    float lt = lloc + __shfl_xor(lloc, 32, 64);  // combine hi halves (same q)
    float* sM = (float*)smem;                    // aliases KV buffers (loop done)
    const int key = (lane & 7) << 2;
    if (jp == 1) {
        float* dst = sM + qh * 2048 + lane * 32;
#pragma unroll
        for (int i = 0; i < 4; ++i) {
            f32x4 t0 = {o0[4 * i], o0[4 * i + 1], o0[4 * i + 2], o0[4 * i + 3]};
            f32x4 t1 = {o1[4 * i], o1[4 * i + 1], o1[4 * i + 2], o1[4 * i + 3]};
            *reinterpret_cast<f32x4*>(dst + ((4 * i) ^ key))      = t0;
            *reinterpret_cast<f32x4*>(dst + ((16 + 4 * i) ^ key)) = t1;
        }
        sMl[qh * 64 + lane] = lt;
    }
    __syncthreads();
    if (jp == 0) {
        const float* src = sM + qh * 2048 + lane * 32;
#pragma unroll
        for (int i = 0; i < 4; ++i) {
            f32x4 t0 = *reinterpret_cast<const f32x4*>(src + ((4 * i) ^ key));
            f32x4 t1 = *reinterpret_cast<const f32x4*>(src + ((16 + 4 * i) ^ key));
#pragma unroll
            for (int r = 0; r < 4; ++r) { o0[4 * i + r] += t0[r]; o1[4 * i + r] += t1[r]; }
        }
        const float linv = 1.0f / (lt + sMl[qh * 64 + lane]);
        float* orow = &Out[(rowbase + q0 + l31) * 512 + hc];
#pragma unroll
        for (int t = 0; t < 4; ++t) {
            f32x4 a, c;
#pragma unroll
            for (int r = 0; r < 4; ++r) {
                a[r] = o0[4 * t + r] * linv;
                c[r] = o1[4 * t + r] * linv;
            }
            *reinterpret_cast<f32x4*>(orow + 8 * t + 4 * hi)      = a;
            *reinterpret_cast<f32x4*>(orow + 32 + 8 * t + 4 * hi) = c;
        }
    }
}

extern "C" void kernel_launch(void* const* d_in, const int* in_sizes, int n_in,
                              void* d_out, int out_size, void* d_ws, size_t ws_size,
                              hipStream_t stream) {
    const float* x   = (const float*)d_in[0];
    const float* pos = (const float*)d_in[1];
    const float* Wq  = (const float*)d_in[2];
    const float* Wk  = (const float*)d_in[3];
    float* out = (float*)d_out;

    // ws (bf16 elems): Q 4.19M | K 4.19M | Vt 4.19M  (~25MB)
    unsigned short* Qb  = (unsigned short*)d_ws;
    unsigned short* Kbf = Qb  + 4194304;
    unsigned short* Vtb = Kbf + 4194304;

    gemm_qk<<<dim3(64, 12), dim3(256), 0, stream>>>(x, Wq, Wk, Qb, Kbf, Vtb);
    attn_fwd<<<dim3(512), dim3(512), 0, stream>>>(Qb, Kbf, Vtb, pos, out);
}

// Round 21
// 75.116 us; speedup vs baseline: 1.0821x; 1.0183x over previous
//
#include <hip/hip_runtime.h>
#include <hip/hip_bf16.h>

typedef __bf16 bf16x8 __attribute__((ext_vector_type(8)));
typedef float f32x4 __attribute__((ext_vector_type(4)));
typedef float f32x16 __attribute__((ext_vector_type(16)));

__device__ inline unsigned short f2bf(float f) {
    __hip_bfloat16 h = __float2bfloat16(f);
    return __builtin_bit_cast(unsigned short, h);
}
// packed RNE f32->bf16 convert (HW op, single instruction): dst = {bf16(a), bf16(b)}
// operand order verified on HW in round 10 (kernel passed absmax 0.0156 using it).
__device__ inline unsigned cvtpk(float a, float b) {
    unsigned r;
    asm("v_cvt_pk_bf16_f32 %0, %1, %2" : "=v"(r) : "v"(a), "v"(b));
    return r;
}
// truncation-pack: dst = {hi16(lo), hi16(hi)} via single v_perm_b32. P in [0,1] ->
// truncation error < 2^-8 relative, negligible (round-20 verified: absmax unchanged).
__device__ inline unsigned pkhi(float lo, float hi) {
    return __builtin_amdgcn_perm(__builtin_bit_cast(unsigned, hi),
                                 __builtin_bit_cast(unsigned, lo), 0x07060302u);
}
__device__ inline float exp2_fast(float x) {
    float r;
    asm("v_exp_f32 %0, %1" : "=v"(r) : "v"(x));
    return r;
}

#define QSCALE 0.1803368801111244f  /* 0.125 * log2(e) */

// ------- fused projection + V-transpose: grid (64, 12) x 256 threads -----------------
// by 0..3:  Q = (x Wq^T) * QSCALE   (128x128 GEMM tile)
// by 4..7:  K = x Wk^T
// by 8..11: V transpose slice: x[b][n][hc+d] -> Vt[b*8+h][d][n'] for h = 2(by-8)+{0,1}.
//           n' = bit2<->bit3 permuted within 16-block (PV fragment contiguous 16B).
// Staging cvt uses HW v_cvt_pk_bf16_f32 (round-21: replaces unfused RNE cast chains;
// bit-identical results).
__global__ __launch_bounds__(256) void gemm_qk(const float* __restrict__ x,
                                               const float* __restrict__ Wq,
                                               const float* __restrict__ Wk,
                                               unsigned short* __restrict__ Qb,
                                               unsigned short* __restrict__ Kb,
                                               unsigned short* __restrict__ Vt) {
    __shared__ __align__(16) unsigned short sA[128 * 40];
    __shared__ __align__(16) unsigned short sB[128 * 40];
    const int tid  = threadIdx.x;
    const int by = blockIdx.y;

    if (by >= 8) {  // ---- V transpose slice ----
        const int q = by - 8;
        const int nl = tid & 127, hh = tid >> 7;
        const int h = q * 2 + hh;
        const int g = blockIdx.x * 128 + nl;       // global row 0..8191
        const int b = g >> 11, n = g & 2047;
        const int np = (n & ~15) | (n & 3) | ((n & 4) << 1) | ((n & 8) >> 1);
        const size_t xrow = ((size_t)b * 2048 + n) * 512 + h * 64;
        const size_t vbase = ((size_t)(b * 8 + h) * 64) * 2048 + np;
#pragma unroll
        for (int d0 = 0; d0 < 64; d0 += 4) {
            float4 v = *reinterpret_cast<const float4*>(&x[xrow + d0]);
            Vt[vbase + (size_t)(d0 + 0) * 2048] = f2bf(v.x);
            Vt[vbase + (size_t)(d0 + 1) * 2048] = f2bf(v.y);
            Vt[vbase + (size_t)(d0 + 2) * 2048] = f2bf(v.z);
            Vt[vbase + (size_t)(d0 + 3) * 2048] = f2bf(v.w);
        }
        return;
    }

    const int lane = tid & 63;
    const int wave = tid >> 6;
    const int wr = wave >> 1, wc = wave & 1;
    const int bm = blockIdx.x * 128;
    const float* __restrict__ Bsrc = (by < 4) ? Wq : Wk;
    unsigned short* __restrict__ C = (by < 4) ? Qb : Kb;
    const int bn = (by & 3) * 128;
    const float scale = (by < 4) ? QSCALE : 1.0f;
    const int tr = tid >> 1, th = (tid & 1) * 16;
    const int rl = lane & 15;
    const int kq = (lane >> 4) * 8;

    f32x4 acc[4][4];
#pragma unroll
    for (int m = 0; m < 4; ++m)
#pragma unroll
        for (int n = 0; n < 4; ++n) acc[m][n] = (f32x4){0.f, 0.f, 0.f, 0.f};

    for (int k0 = 0; k0 < 512; k0 += 32) {
        const float* ap = &x[(size_t)(bm + tr) * 512 + k0 + th];
        const float* bp = &Bsrc[(size_t)(bn + tr) * 512 + k0 + th];
        float4 a0 = *reinterpret_cast<const float4*>(ap);
        float4 a1 = *reinterpret_cast<const float4*>(ap + 4);
        float4 a2 = *reinterpret_cast<const float4*>(ap + 8);
        float4 a3 = *reinterpret_cast<const float4*>(ap + 12);
        float4 b0 = *reinterpret_cast<const float4*>(bp);
        float4 b1 = *reinterpret_cast<const float4*>(bp + 4);
        float4 b2 = *reinterpret_cast<const float4*>(bp + 8);
        float4 b3 = *reinterpret_cast<const float4*>(bp + 12);
        uint4 pa0 = {cvtpk(a0.x, a0.y), cvtpk(a0.z, a0.w), cvtpk(a1.x, a1.y), cvtpk(a1.z, a1.w)};
        uint4 pa1 = {cvtpk(a2.x, a2.y), cvtpk(a2.z, a2.w), cvtpk(a3.x, a3.y), cvtpk(a3.z, a3.w)};
        uint4 pb0 = {cvtpk(b0.x, b0.y), cvtpk(b0.z, b0.w), cvtpk(b1.x, b1.y), cvtpk(b1.z, b1.w)};
        uint4 pb1 = {cvtpk(b2.x, b2.y), cvtpk(b2.z, b2.w), cvtpk(b3.x, b3.y), cvtpk(b3.z, b3.w)};
        __syncthreads();
        *reinterpret_cast<uint4*>(&sA[tr * 40 + th])     = pa0;
        *reinterpret_cast<uint4*>(&sA[tr * 40 + th + 8]) = pa1;
        *reinterpret_cast<uint4*>(&sB[tr * 40 + th])     = pb0;
        *reinterpret_cast<uint4*>(&sB[tr * 40 + th + 8]) = pb1;
        __syncthreads();

        bf16x8 af[4], bfv[4];
#pragma unroll
        for (int m = 0; m < 4; ++m)
            af[m] = __builtin_bit_cast(bf16x8,
                *reinterpret_cast<const uint4*>(&sA[(wr * 64 + m * 16 + rl) * 40 + kq]));
#pragma unroll
        for (int n = 0; n < 4; ++n)
            bfv[n] = __builtin_bit_cast(bf16x8,
                *reinterpret_cast<const uint4*>(&sB[(wc * 64 + n * 16 + rl) * 40 + kq]));
#pragma unroll
        for (int m = 0; m < 4; ++m)
#pragma unroll
            for (int n = 0; n < 4; ++n)
                acc[m][n] = __builtin_amdgcn_mfma_f32_16x16x32_bf16(af[m], bfv[n], acc[m][n], 0, 0, 0);
    }

    const int rq = (lane >> 4) * 4;
#pragma unroll
    for (int m = 0; m < 4; ++m) {
        int r = bm + wr * 64 + m * 16 + rq;
#pragma unroll
        for (int n = 0; n < 4; ++n) {
            int c = bn + wc * 64 + n * 16 + rl;
#pragma unroll
            for (int reg = 0; reg < 4; ++reg)
                C[(size_t)(r + reg) * 512 + c] = f2bf(acc[m][n][reg] * scale);
        }
    }
}

// ---------------- fused flash attention: 8 waves (4qh x 2jp), dbuf, 1 barrier/tile ---
// grid: 512 flat blocks, XCD bh-affinity (xcd=flat&7 owns bh {4xcd..4xcd+3}) -> per-XCD
// K/V working set 2MB, L2-resident. block: 512 = 8 waves; wave: qh=w&3, jp=w>>2.
// Fixed-reference softmax in log2 domain (log2e folded into Q-scale and slope).
// One-time sPos table (slopeL*pos, 8KB LDS) removes pos staging from the loop.
// P-pack via single v_perm_b32 truncation per pair (round-20 verified win).
// S^T: mfma(K,Q) -> D[row=j][col=q]: lane q=l31, j=(r&3)+8*(r>>2)+4*hi.
// PV: P-frag lane-local, j-map = 16ks + 4hi + (e&3) + 8*(e>>2); V pre-permuted so this
// fragment is one contiguous b128 read. LDS rows XOR-swizzled (byte ^= (row&7)<<4).
__global__ __launch_bounds__(512, 4) void attn_fwd(const unsigned short* __restrict__ Q,
                                                   const unsigned short* __restrict__ Kb,
                                                   const unsigned short* __restrict__ Vt,
                                                   const float* __restrict__ pos,
                                                   float* __restrict__ Out) {
    __shared__ __align__(16) unsigned char smem[42240];
    char* k0b = (char*)smem;                 // 8 KiB
    char* v0b = (char*)smem + 8192;          // 8 KiB
    char* k1b = (char*)smem + 16384;         // 8 KiB
    char* v1b = (char*)smem + 24576;         // 8 KiB
    float* sPosT = (float*)(smem + 32768);   // 2048 f32 slopeL*pos (8 KiB)
    float* sMl   = (float*)(smem + 40960);   // 256 f32 (epilogue l merge)

    const int tid  = threadIdx.x;
    const int lane = tid & 63;
    const int w    = tid >> 6;
    const int l31  = lane & 31;
    const int hi   = lane >> 5;
    const int qh   = w & 3;
    const int jp   = w >> 2;
    // XCD-affine decode (512 blocks, bijective: 512 % 8 == 0)
    const int flat = blockIdx.x;
    const int xcd  = flat & 7;
    const int idx  = flat >> 3;              // 0..63
    const int bh   = xcd * 4 + (idx >> 4);
    const int qt   = idx & 15;
    const int b = bh >> 3, h = bh & 7;
    const int q0 = qt * 128 + qh * 32;
    const size_t rowbase = (size_t)b * 2048;
    const int hc = h * 64;
    const float slopeL = ldexpf(1.4426950408889634f, -(h + 1));  // slope * log2(e)

    // Q B-fragments: lane supplies Q[q=l31][c = ks*16 + hi*8 + e] (Q pre-scaled)
    bf16x8 qf0, qf1, qf2, qf3;
    {
        const unsigned short* qp = &Q[(rowbase + q0 + l31) * 512 + hc + hi * 8];
        qf0 = __builtin_bit_cast(bf16x8, *reinterpret_cast<const uint4*>(qp));
        qf1 = __builtin_bit_cast(bf16x8, *reinterpret_cast<const uint4*>(qp + 16));
        qf2 = __builtin_bit_cast(bf16x8, *reinterpret_cast<const uint4*>(qp + 32));
        qf3 = __builtin_bit_cast(bf16x8, *reinterpret_cast<const uint4*>(qp + 48));
    }
    const float ui = slopeL * pos[rowbase + q0 + l31];

    // one-time slopeL*pos table (512 threads x 4 = 2048)
    {
        float4 v = reinterpret_cast<const float4*>(pos + rowbase)[tid];
        reinterpret_cast<f32x4*>(sPosT)[tid] =
            (f32x4){v.x * slopeL, v.y * slopeL, v.z * slopeL, v.w * slopeL};
    }

    float lloc = 0.f;
    f32x16 o0, o1;
#pragma unroll
    for (int r = 0; r < 16; ++r) { o0[r] = 0.f; o1[r] = 0.f; }

    // staging: 8 threads/row x 16 B; write slot XOR-swizzled -> conflict-free
    const int sr  = tid >> 3;                       // row 0..63
    const int sce = (tid & 7) * 8;                  // elem col (8 elems/thread)
    const int wbyte = sr * 128 + (((tid & 7) * 16) ^ ((sr & 7) << 4));
    const int kswz = (l31 & 7) << 4;                // compute-side swizzle key

    uint4 ck, cv;

    auto stage = [&](int j0v) {
        ck = *reinterpret_cast<const uint4*>(&Kb[(rowbase + j0v + sr) * 512 + hc + sce]);
        cv = *reinterpret_cast<const uint4*>(&Vt[((size_t)bh * 64 + sr) * 2048 + j0v + sce]);
    };
    auto writeb = [&](char* KB, char* VB) {
        *reinterpret_cast<uint4*>(KB + wbyte) = ck;
        *reinterpret_cast<uint4*>(VB + wbyte) = cv;
    };
    auto compute = [&](const char* KB, const char* VB, int j0) {
        const char* kr = KB + (32 * jp + l31) * 128;
        // ---- S chunk (32j x 32q) for this wave's (qh, jp) ----
        f32x16 s;
#pragma unroll
        for (int r = 0; r < 16; ++r) s[r] = 0.f;
        __builtin_amdgcn_s_setprio(1);
#pragma unroll
        for (int ks = 0; ks < 4; ++ks) {
            bf16x8 kf = __builtin_bit_cast(bf16x8,
                *reinterpret_cast<const uint4*>(kr + ((ks * 32 + hi * 16) ^ kswz)));
            bf16x8 qq = (ks == 0) ? qf0 : (ks == 1) ? qf1 : (ks == 2) ? qf2 : qf3;
            s = __builtin_amdgcn_mfma_f32_32x32x16_bf16(kf, qq, s, 0, 0, 0);
        }
        __builtin_amdgcn_s_setprio(0);

        // ---- bias + exp2 (fixed reference, log2 domain) ----
        float ls = 0.f;
#pragma unroll
        for (int t = 0; t < 4; ++t) {
            f32x4 u = *reinterpret_cast<const f32x4*>(&sPosT[j0 + 32 * jp + 8 * t + 4 * hi]);
#pragma unroll
            for (int r = 0; r < 4; ++r) {
                float p = exp2_fast(s[4 * t + r] - fabsf(u[r] - ui));
                s[4 * t + r] = p;
                ls += p;
            }
        }
        lloc += ls;

        // ---- lane-local P fragments (j = 16ks + 4hi + (e&3) + 8*(e>>2)) ----
        // single-instruction truncation pack per bf16 pair (v_perm_b32)
        bf16x8 pf0 = __builtin_bit_cast(bf16x8, (uint4){
            pkhi(s[0], s[1]),  pkhi(s[2], s[3]),   pkhi(s[4], s[5]),   pkhi(s[6], s[7])});
        bf16x8 pf1 = __builtin_bit_cast(bf16x8, (uint4){
            pkhi(s[8], s[9]),  pkhi(s[10], s[11]), pkhi(s[12], s[13]), pkhi(s[14], s[15])});

        // ---- PV: O^T[d][q] += V-frag x P-frag; V pre-permuted -> single b128/frag ----
        const char* vr0 = VB + l31 * 128;
        const char* vr1 = VB + (32 + l31) * 128;
        __builtin_amdgcn_s_setprio(1);
#pragma unroll
        for (int ks = 0; ks < 2; ++ks) {
            const int cb = (64 * jp + ks * 32 + hi * 16) ^ kswz;  // permuted-stored
            bf16x8 v0 = __builtin_bit_cast(bf16x8, *reinterpret_cast<const uint4*>(vr0 + cb));
            bf16x8 v1 = __builtin_bit_cast(bf16x8, *reinterpret_cast<const uint4*>(vr1 + cb));
            bf16x8 pf = ks ? pf1 : pf0;
            o0 = __builtin_amdgcn_mfma_f32_32x32x16_bf16(v0, pf, o0, 0, 0, 0);
            o1 = __builtin_amdgcn_mfma_f32_32x32x16_bf16(v1, pf, o1, 0, 0, 0);
        }
        __builtin_amdgcn_s_setprio(0);
    };

    // prologue: tile 0 -> buf0; tile 1 -> regs
    stage(0);
    writeb(k0b, v0b);
    stage(64);
    __syncthreads();

    for (int t = 0; t < 32; t += 2) {
        // even iter: compute buf0, regs hold tile t+1 -> buf1
        writeb(k1b, v1b);
        if (t + 2 < 32) stage((t + 2) * 64);
        compute(k0b, v0b, t * 64);
        __syncthreads();
        // odd iter: compute buf1, regs hold tile t+2 -> buf0
        if (t + 2 < 32) {
            writeb(k0b, v0b);
            if (t + 3 < 32) stage((t + 3) * 64);
        }
        compute(k1b, v1b, (t + 1) * 64);
        __syncthreads();
    }

    // ---- epilogue: merge jp partials via LDS, normalize, direct 16B stores ----
    float lt = lloc + __shfl_xor(lloc, 32, 64);  // combine hi halves (same q)
    float* sM = (float*)smem;                    // aliases KV buffers (loop done)
    const int key = (lane & 7) << 2;
    if (jp == 1) {
        float* dst = sM + qh * 2048 + lane * 32;
#pragma unroll
        for (int i = 0; i < 4; ++i) {
            f32x4 t0 = {o0[4 * i], o0[4 * i + 1], o0[4 * i + 2], o0[4 * i + 3]};
            f32x4 t1 = {o1[4 * i], o1[4 * i + 1], o1[4 * i + 2], o1[4 * i + 3]};
            *reinterpret_cast<f32x4*>(dst + ((4 * i) ^ key))      = t0;
            *reinterpret_cast<f32x4*>(dst + ((16 + 4 * i) ^ key)) = t1;
        }
        sMl[qh * 64 + lane] = lt;
    }
    __syncthreads();
    if (jp == 0) {
        const float* src = sM + qh * 2048 + lane * 32;
#pragma unroll
        for (int i = 0; i < 4; ++i) {
            f32x4 t0 = *reinterpret_cast<const f32x4*>(src + ((4 * i) ^ key));
            f32x4 t1 = *reinterpret_cast<const f32x4*>(src + ((16 + 4 * i) ^ key));
#pragma unroll
            for (int r = 0; r < 4; ++r) { o0[4 * i + r] += t0[r]; o1[4 * i + r] += t1[r]; }
        }
        const float linv = 1.0f / (lt + sMl[qh * 64 + lane]);
        float* orow = &Out[(rowbase + q0 + l31) * 512 + hc];
#pragma unroll
        for (int t = 0; t < 4; ++t) {
            f32x4 a, c;
#pragma unroll
            for (int r = 0; r < 4; ++r) {
                a[r] = o0[4 * t + r] * linv;
                c[r] = o1[4 * t + r] * linv;
            }
            *reinterpret_cast<f32x4*>(orow + 8 * t + 4 * hi)      = a;
            *reinterpret_cast<f32x4*>(orow + 32 + 8 * t + 4 * hi) = c;
        }
    }
}

extern "C" void kernel_launch(void* const* d_in, const int* in_sizes, int n_in,
                              void* d_out, int out_size, void* d_ws, size_t ws_size,
                              hipStream_t stream) {
    const float* x   = (const float*)d_in[0];
    const float* pos = (const float*)d_in[1];
    const float* Wq  = (const float*)d_in[2];
    const float* Wk  = (const float*)d_in[3];
    float* out = (float*)d_out;

    // ws (bf16 elems): Q 4.19M | K 4.19M | Vt 4.19M  (~25MB)
    unsigned short* Qb  = (unsigned short*)d_ws;
    unsigned short* Kbf = Qb  + 4194304;
    unsigned short* Vtb = Kbf + 4194304;

    gemm_qk<<<dim3(64, 12), dim3(256), 0, stream>>>(x, Wq, Wk, Qb, Kbf, Vtb);
    attn_fwd<<<dim3(512), dim3(512), 0, stream>>>(Qb, Kbf, Vtb, pos, out);
}